// Round 9
// baseline (1656.972 us; speedup 1.0000x reference)
//
#include <hip/hip_runtime.h>
#include <hip/hip_bf16.h>

// R9: R5 kernel (best, 202.8us) restored verbatim + two pure-read BW
// diagnostic kernels (5 passes over x each, ~600-1000us, so they appear in
// the rocprof top-5 above the ~490us harness fills).
//   diag_read_stream : canonical grid-stride float4 read        -> ws
//   diag_read_r5pat  : R5's exact per-thread row/chunk pattern  -> ws
#define DIM    768
#define NC     53
#define NCP    64
#define MTB    256
#define NTH    512
#define KSTEP  32
#define NSTEPS 24
#define APAD   40
#define DIAG_REPS 5

typedef __attribute__((ext_vector_type(8))) short short8;
typedef __attribute__((ext_vector_type(4))) float f32x4;

static __device__ inline unsigned short f2bf(float f) {
    unsigned u = __float_as_uint(f);
    u += 0x7fff + ((u >> 16) & 1);           // RNE
    return (unsigned short)(u >> 16);
}

__global__ void wconv_kernel(const float* __restrict__ W, unsigned short* __restrict__ Wt) {
    const int idx = blockIdx.x * 256 + threadIdx.x;
    if (idx >= NCP * DIM) return;
    const int c = idx / DIM, k = idx - c * DIM;
    Wt[idx] = f2bf((c < NC) ? W[c * DIM + k] : 0.f);
}

static __device__ inline void cvt_store(unsigned short* dst, const float4* r) {
    union { short8 v; unsigned short u[8]; } a, b;
    a.u[0]=f2bf(r[0].x); a.u[1]=f2bf(r[0].y); a.u[2]=f2bf(r[0].z); a.u[3]=f2bf(r[0].w);
    a.u[4]=f2bf(r[1].x); a.u[5]=f2bf(r[1].y); a.u[6]=f2bf(r[1].z); a.u[7]=f2bf(r[1].w);
    b.u[0]=f2bf(r[2].x); b.u[1]=f2bf(r[2].y); b.u[2]=f2bf(r[2].z); b.u[3]=f2bf(r[2].w);
    b.u[4]=f2bf(r[3].x); b.u[5]=f2bf(r[3].y); b.u[6]=f2bf(r[3].z); b.u[7]=f2bf(r[3].w);
    *reinterpret_cast<short8*>(dst)     = a.v;
    *reinterpret_cast<short8*>(dst + 8) = b.v;
}

__global__ __launch_bounds__(NTH) void bag_attn_mfma(
    const float* __restrict__ x,
    const unsigned short* __restrict__ Wt,
    const float* __restrict__ bias,
    const int*   __restrict__ query,
    float*       __restrict__ out)
{
    __shared__ __align__(16) unsigned short Ab[2][MTB * APAD];
    __shared__ float att_sm[16][16];
    __shared__ int   qbuf[MTB];

    const int t   = threadIdx.x;
    const int w   = t >> 6;
    const int l   = t & 63;
    const int blk = blockIdx.x;
    const int row_g = blk * MTB;

    if (t < MTB) qbuf[t] = query[row_g + t];

    const int srow  = t >> 1;
    const int shalf = t & 1;
    const float4* x4 = reinterpret_cast<const float4*>(x)
                     + (size_t)(row_g + srow) * (DIM / 4) + shalf * 4;
    unsigned short* dst0 = &Ab[0][srow * APAD + shalf * 16];
    unsigned short* dst1 = &Ab[1][srow * APAD + shalf * 16];

    f32x4 acc[2][4];
    #pragma unroll
    for (int mi = 0; mi < 2; ++mi)
        #pragma unroll
        for (int ni = 0; ni < 4; ++ni)
            acc[mi][ni] = (f32x4){0.f, 0.f, 0.f, 0.f};

    float4 rA[4], rB[4];
    #pragma unroll
    for (int m = 0; m < 4; ++m) rA[m] = x4[0 * 8 + m];
    #pragma unroll
    for (int m = 0; m < 4; ++m) rB[m] = x4[1 * 8 + m];
    cvt_store(dst0, rA);
    __syncthreads();

#define COMPUTE(p, kk)                                                         \
    {                                                                          \
        short8 bfr[4];                                                         \
        _Pragma("unroll")                                                      \
        for (int ni = 0; ni < 4; ++ni)                                         \
            bfr[ni] = *reinterpret_cast<const short8*>(                        \
                Wt + ((16 * ni + (l & 15)) * DIM + (kk) * KSTEP + (l >> 4) * 8)); \
        short8 afr[2];                                                         \
        _Pragma("unroll")                                                      \
        for (int mi = 0; mi < 2; ++mi)                                         \
            afr[mi] = *reinterpret_cast<const short8*>(                        \
                &Ab[p][(32 * w + 16 * mi + (l & 15)) * APAD + (l >> 4) * 8]);  \
        _Pragma("unroll")                                                      \
        for (int mi = 0; mi < 2; ++mi)                                         \
            _Pragma("unroll")                                                  \
            for (int ni = 0; ni < 4; ++ni)                                     \
                acc[mi][ni] = __builtin_amdgcn_mfma_f32_16x16x32_bf16(         \
                    afr[mi], bfr[ni], acc[mi][ni], 0, 0, 0);                   \
    }

    for (int kk = 0; kk < NSTEPS; kk += 2) {
        if (kk + 2 < NSTEPS) {
            #pragma unroll
            for (int m = 0; m < 4; ++m) rA[m] = x4[(kk + 2) * 8 + m];
        }
        COMPUTE(0, kk);
        cvt_store(dst1, rB);
        __syncthreads();
        if (kk + 3 < NSTEPS) {
            #pragma unroll
            for (int m = 0; m < 4; ++m) rB[m] = x4[(kk + 3) * 8 + m];
        }
        COMPUTE(1, kk + 1);
        if (kk + 2 < NSTEPS) {
            cvt_store(dst0, rA);
            __syncthreads();
        }
    }
#undef COMPUTE

    #pragma unroll
    for (int mi = 0; mi < 2; ++mi) {
        #pragma unroll
        for (int r = 0; r < 4; ++r) {
            const int s_loc = ((l >> 4) << 2) + r;
            const int q = qbuf[32 * w + 16 * mi + s_loc];
            if ((q & 15) == (l & 15)) {
                float v = acc[mi][0][r];
                if ((q >> 4) == 1) v = acc[mi][1][r];
                if ((q >> 4) == 2) v = acc[mi][2][r];
                if ((q >> 4) == 3) v = acc[mi][3][r];
                att_sm[2 * w + mi][s_loc] = v;
            }
        }
    }
    __syncthreads();

    #pragma unroll
    for (int mi = 0; mi < 2; ++mi) {
        const int bag = 2 * w + mi;
        const float4* a4 = reinterpret_cast<const float4*>(&att_sm[bag][0]);
        const float4 A0 = a4[0], A1 = a4[1], A2 = a4[2], A3 = a4[3];
        float mx = fmaxf(fmaxf(fmaxf(A0.x, A0.y), fmaxf(A0.z, A0.w)),
                  fmaxf(fmaxf(fmaxf(A1.x, A1.y), fmaxf(A1.z, A1.w)),
                  fmaxf(fmaxf(fmaxf(A2.x, A2.y), fmaxf(A2.z, A2.w)),
                        fmaxf(fmaxf(A3.x, A3.y), fmaxf(A3.z, A3.w)))));
        float zz = __expf(A0.x-mx)+__expf(A0.y-mx)+__expf(A0.z-mx)+__expf(A0.w-mx)
                 + __expf(A1.x-mx)+__expf(A1.y-mx)+__expf(A1.z-mx)+__expf(A1.w-mx)
                 + __expf(A2.x-mx)+__expf(A2.y-mx)+__expf(A2.z-mx)+__expf(A2.w-mx)
                 + __expf(A3.x-mx)+__expf(A3.y-mx)+__expf(A3.z-mx)+__expf(A3.w-mx);
        const float inv = 1.f / zz;
        const int grp = l >> 4;
        float4 As = A0;
        if (grp == 1) As = A1;
        if (grp == 2) As = A2;
        if (grp == 3) As = A3;
        const float w0 = __expf(As.x - mx) * inv;
        const float w1 = __expf(As.y - mx) * inv;
        const float w2 = __expf(As.z - mx) * inv;
        const float w3 = __expf(As.w - mx) * inv;
        #pragma unroll
        for (int ni = 0; ni < 4; ++ni) {
            float p = w0 * acc[mi][ni][0] + w1 * acc[mi][ni][1]
                    + w2 * acc[mi][ni][2] + w3 * acc[mi][ni][3];
            p += __shfl_xor(p, 16, 64);
            p += __shfl_xor(p, 32, 64);
            if (l < 16) {
                const int c = 16 * ni + l;
                if (c < NC)
                    out[(size_t)(blk * 16 + bag) * NC + c] = p + bias[c];
            }
        }
    }
}

// ---- diagnostic 1: canonical grid-stride float4 pure-read ----
__global__ __launch_bounds__(256) void diag_read_stream(
    const float4* __restrict__ x, float* __restrict__ ws, int n4)
{
    const long long tid    = (long long)blockIdx.x * 256 + threadIdx.x;
    const long long stride = (long long)gridDim.x * 256;
    float s = 0.f;
    for (int rep = 0; rep < DIAG_REPS; ++rep) {
        for (long long i = tid; i < n4; i += stride) {
            const float4 v = x[i];
            s += v.x + v.y + v.z + v.w;
        }
    }
    ws[tid] = s;
}

// ---- diagnostic 2: R5's exact per-thread access pattern, loads only ----
__global__ __launch_bounds__(NTH) void diag_read_r5pat(
    const float* __restrict__ x, float* __restrict__ ws)
{
    const int t = threadIdx.x;
    const int srow  = t >> 1;
    const int shalf = t & 1;
    const float4* x4 = reinterpret_cast<const float4*>(x)
                     + (size_t)(blockIdx.x * MTB + srow) * (DIM / 4) + shalf * 4;
    float s = 0.f;
    for (int rep = 0; rep < DIAG_REPS; ++rep) {
        for (int k = 0; k < NSTEPS; ++k) {
            #pragma unroll
            for (int m = 0; m < 4; ++m) {
                const float4 v = x4[k * 8 + m];
                s += v.x + v.y + v.z + v.w;
            }
        }
    }
    ws[(long long)blockIdx.x * NTH + t] = s;
}

extern "C" void kernel_launch(void* const* d_in, const int* in_sizes, int n_in,
                              void* d_out, int out_size, void* d_ws, size_t ws_size,
                              hipStream_t stream) {
    const float* x     = (const float*)d_in[0];
    const float* W     = (const float*)d_in[1];
    const float* bias  = (const float*)d_in[2];
    const int*   query = (const int*)d_in[4];
    float* out = (float*)d_out;

    unsigned short* Wt = (unsigned short*)d_ws;           // 96 KiB
    float* diag = (float*)((char*)d_ws + (1 << 20));      // diag scratch

    const int nrows = in_sizes[0] / DIM;                  // 262144
    const int nblk  = nrows / MTB;                        // 1024
    const int n4    = in_sizes[0] / 4;                    // 50,331,648 float4

    wconv_kernel<<<(NCP * DIM + 255) / 256, 256, 0, stream>>>(W, Wt);
    bag_attn_mfma<<<nblk, NTH, 0, stream>>>(x, Wt, bias, query, out);

    diag_read_stream<<<2048, 256, 0, stream>>>(
        reinterpret_cast<const float4*>(x), diag, n4);
    diag_read_r5pat<<<nblk, NTH, 0, stream>>>(
        x, diag + 2048 * 256);
}

// Round 10
// 192.138 us; speedup vs baseline: 8.6239x; 8.6239x over previous
//
#include <hip/hip_runtime.h>
#include <hip/hip_bf16.h>

// N=262144 sentences (uniform 16/bag, contiguous), D=768, C=53
// Y = X * W^T [N x 53] via bf16 MFMA (R5 structure). R10 change: staging
// lane-map gives cache-line-complete wave loads (8 x 128B lines per
// instruction) instead of 64 scattered 16B segments — fixes the request-rate
// bottleneck measured in R9 (4.9 -> 6.4 TB/s logical read).
#define DIM    768
#define NC     53
#define NCP    64        // classes padded to 4 MFMA n-tiles
#define MTB    256       // sentences per block (= 16 bags)
#define NTH    512       // 8 waves
#define KSTEP  32
#define NSTEPS 24        // 768 / 32
#define APAD   40        // LDS row stride in bf16 (80 B rows)

typedef __attribute__((ext_vector_type(8))) short short8;
typedef __attribute__((ext_vector_type(4))) float f32x4;

static __device__ inline unsigned short f2bf(float f) {
    unsigned u = __float_as_uint(f);
    u += 0x7fff + ((u >> 16) & 1);           // RNE
    return (unsigned short)(u >> 16);
}

// ---- kernel 1: W fp32 [53][768] -> bf16 [64][768] in d_ws ----
__global__ void wconv_kernel(const float* __restrict__ W, unsigned short* __restrict__ Wt) {
    const int idx = blockIdx.x * 256 + threadIdx.x;
    if (idx >= NCP * DIM) return;
    const int c = idx / DIM, k = idx - c * DIM;
    Wt[idx] = f2bf((c < NC) ? W[c * DIM + k] : 0.f);
}

// 4 fp32 -> 4 bf16 (8 B) via packed cvt
static __device__ inline void cvt_store8(unsigned short* dst, const float4 v) {
    union { __hip_bfloat162 h[2]; uint2 u; } z;
    z.h[0] = __float22bfloat162_rn(make_float2(v.x, v.y));
    z.h[1] = __float22bfloat162_rn(make_float2(v.z, v.w));
    *reinterpret_cast<uint2*>(dst) = z.u;
}

__global__ __launch_bounds__(NTH) void bag_attn_mfma4(
    const float* __restrict__ x,              // [N][768] fp32
    const unsigned short* __restrict__ Wt,    // [64][768] bf16 (d_ws)
    const float* __restrict__ bias,           // [53]
    const int*   __restrict__ query,          // [N]
    float*       __restrict__ out)            // [B][53]
{
    __shared__ __align__(16) unsigned short Ab[2][MTB * APAD];  // 40 KiB
    __shared__ float att_sm[16][16];
    __shared__ int   qbuf[MTB];

    const int t   = threadIdx.x;
    const int w   = t >> 6;        // wave 0..7 -> rows 32w..32w+31 (bags 2w,2w+1)
    const int l   = t & 63;
    const int blk = blockIdx.x;
    const int row_g = blk * MTB;

    if (t < MTB) qbuf[t] = query[row_g + t];

    // staging map (cache-line-complete): load i, lane l ->
    //   row = 32w + 8i + (l>>3), 16B at byte (l&7)*16 of the row's 128B k-chunk
    const float4* xp = reinterpret_cast<const float4*>(x)
                     + (size_t)(row_g + 32 * w + (l >> 3)) * (DIM / 4) + (l & 7);
    unsigned short* d0[4];
    unsigned short* d1[4];
    #pragma unroll
    for (int i = 0; i < 4; ++i) {
        const int off = (32 * w + 8 * i + (l >> 3)) * APAD + (l & 7) * 4;
        d0[i] = &Ab[0][off];
        d1[i] = &Ab[1][off];
    }

    f32x4 acc[2][4];
    #pragma unroll
    for (int mi = 0; mi < 2; ++mi)
        #pragma unroll
        for (int ni = 0; ni < 4; ++ni)
            acc[mi][ni] = (f32x4){0.f, 0.f, 0.f, 0.f};

    float4 rA[4], rB[4];
    #pragma unroll
    for (int i = 0; i < 4; ++i) rA[i] = xp[i * 8 * (DIM / 4) + 0 * 8];  // tile 0
    #pragma unroll
    for (int i = 0; i < 4; ++i) rB[i] = xp[i * 8 * (DIM / 4) + 1 * 8];  // tile 1
    #pragma unroll
    for (int i = 0; i < 4; ++i) cvt_store8(d0[i], rA[i]);
    __syncthreads();

#define COMPUTE(p, kk)                                                         \
    {                                                                          \
        short8 bfr[4];                                                         \
        _Pragma("unroll")                                                      \
        for (int ni = 0; ni < 4; ++ni)                                         \
            bfr[ni] = *reinterpret_cast<const short8*>(                        \
                Wt + ((16 * ni + (l & 15)) * DIM + (kk) * KSTEP + (l >> 4) * 8)); \
        short8 afr[2];                                                         \
        _Pragma("unroll")                                                      \
        for (int mi = 0; mi < 2; ++mi)                                         \
            afr[mi] = *reinterpret_cast<const short8*>(                        \
                &Ab[p][(32 * w + 16 * mi + (l & 15)) * APAD + (l >> 4) * 8]);  \
        _Pragma("unroll")                                                      \
        for (int mi = 0; mi < 2; ++mi)                                         \
            _Pragma("unroll")                                                  \
            for (int ni = 0; ni < 4; ++ni)                                     \
                acc[mi][ni] = __builtin_amdgcn_mfma_f32_16x16x32_bf16(         \
                    afr[mi], bfr[ni], acc[mi][ni], 0, 0, 0);                   \
    }

    for (int kk = 0; kk < NSTEPS; kk += 2) {
        // even phase: compute buf0 = tile kk; stage tile kk+1 -> buf1
        if (kk + 2 < NSTEPS) {
            #pragma unroll
            for (int i = 0; i < 4; ++i)
                rA[i] = xp[i * 8 * (DIM / 4) + (kk + 2) * 8];
        }
        COMPUTE(0, kk);
        #pragma unroll
        for (int i = 0; i < 4; ++i) cvt_store8(d1[i], rB[i]);
        __syncthreads();
        // odd phase: compute buf1 = tile kk+1; stage tile kk+2 -> buf0
        if (kk + 3 < NSTEPS) {
            #pragma unroll
            for (int i = 0; i < 4; ++i)
                rB[i] = xp[i * 8 * (DIM / 4) + (kk + 3) * 8];
        }
        COMPUTE(1, kk + 1);
        if (kk + 2 < NSTEPS) {
            #pragma unroll
            for (int i = 0; i < 4; ++i) cvt_store8(d0[i], rA[i]);
            __syncthreads();
        }
    }
#undef COMPUTE

    // ---- epilogue: att extraction (D-layout: col=lane&15, row=(l>>4)*4+reg) ----
    #pragma unroll
    for (int mi = 0; mi < 2; ++mi) {
        #pragma unroll
        for (int r = 0; r < 4; ++r) {
            const int s_loc = ((l >> 4) << 2) + r;
            const int q = qbuf[32 * w + 16 * mi + s_loc];
            if ((q & 15) == (l & 15)) {       // one lane per row matches
                float v = acc[mi][0][r];
                if ((q >> 4) == 1) v = acc[mi][1][r];
                if ((q >> 4) == 2) v = acc[mi][2][r];
                if ((q >> 4) == 3) v = acc[mi][3][r];
                att_sm[2 * w + mi][s_loc] = v;
            }
        }
    }
    // att_sm rows 2w,2w+1 written+read by wave w only

    #pragma unroll
    for (int mi = 0; mi < 2; ++mi) {
        const int bag = 2 * w + mi;
        const float4* a4 = reinterpret_cast<const float4*>(&att_sm[bag][0]);
        const float4 A0 = a4[0], A1 = a4[1], A2 = a4[2], A3 = a4[3];
        float mx = fmaxf(fmaxf(fmaxf(A0.x, A0.y), fmaxf(A0.z, A0.w)),
                  fmaxf(fmaxf(fmaxf(A1.x, A1.y), fmaxf(A1.z, A1.w)),
                  fmaxf(fmaxf(fmaxf(A2.x, A2.y), fmaxf(A2.z, A2.w)),
                        fmaxf(fmaxf(A3.x, A3.y), fmaxf(A3.z, A3.w)))));
        float zz = __expf(A0.x-mx)+__expf(A0.y-mx)+__expf(A0.z-mx)+__expf(A0.w-mx)
                 + __expf(A1.x-mx)+__expf(A1.y-mx)+__expf(A1.z-mx)+__expf(A1.w-mx)
                 + __expf(A2.x-mx)+__expf(A2.y-mx)+__expf(A2.z-mx)+__expf(A2.w-mx)
                 + __expf(A3.x-mx)+__expf(A3.y-mx)+__expf(A3.z-mx)+__expf(A3.w-mx);
        const float inv = 1.f / zz;
        const int grp = l >> 4;
        float4 As = A0;
        if (grp == 1) As = A1;
        if (grp == 2) As = A2;
        if (grp == 3) As = A3;
        const float w0 = __expf(As.x - mx) * inv;
        const float w1 = __expf(As.y - mx) * inv;
        const float w2 = __expf(As.z - mx) * inv;
        const float w3 = __expf(As.w - mx) * inv;
        #pragma unroll
        for (int ni = 0; ni < 4; ++ni) {
            float p = w0 * acc[mi][ni][0] + w1 * acc[mi][ni][1]
                    + w2 * acc[mi][ni][2] + w3 * acc[mi][ni][3];
            p += __shfl_xor(p, 16, 64);       // sum the 4 row-groups
            p += __shfl_xor(p, 32, 64);
            if (l < 16) {
                const int c = 16 * ni + l;
                if (c < NC)
                    out[(size_t)(blk * 16 + bag) * NC + c] = p + bias[c];
            }
        }
    }
}

extern "C" void kernel_launch(void* const* d_in, const int* in_sizes, int n_in,
                              void* d_out, int out_size, void* d_ws, size_t ws_size,
                              hipStream_t stream) {
    const float* x     = (const float*)d_in[0];   // [N][768]
    const float* W     = (const float*)d_in[1];   // [53][768]
    const float* bias  = (const float*)d_in[2];   // [53]
    const int*   query = (const int*)d_in[4];     // [N]
    float* out = (float*)d_out;                   // [B][53]

    unsigned short* Wt = (unsigned short*)d_ws;   // 64*768*2 = 96 KiB

    const int nrows = in_sizes[0] / DIM;          // 262144
    const int nblk  = nrows / MTB;                // 1024

    wconv_kernel<<<(NCP * DIM + 255) / 256, 256, 0, stream>>>(W, Wt);
    bag_attn_mfma4<<<nblk, NTH, 0, stream>>>(x, Wt, bias, query, out);
}